// Round 1
// baseline (2570.198 us; speedup 1.0000x reference)
//
#include <hip/hip_runtime.h>

#define NB 16
#define HH 512
#define WW 512
#define HWN (HH * WW)            // 262144 = 1<<18
#define SENT HWN                  // background sentinel
#define KC 512                    // max regions kept per image
#define RCAP 4096                 // root-collection capacity per image
#define PN (NB * HWN)
#define TPB 256
#define IMAX 0x7FFFFFFF

// ---------------- union-find helpers ----------------
__device__ __forceinline__ int findRoot(int* L, int i) {
    int p = L[i];
    while (p != i) { i = p; p = L[i]; }
    return i;
}

__device__ __forceinline__ void unite(int* L, int a, int b) {
    int ra = findRoot(L, a);
    int rb = findRoot(L, b);
    while (ra != rb) {
        int lo = min(ra, rb), hi = max(ra, rb);
        int old = atomicMin(&L[hi], lo);
        if (old == hi) return;   // hi was root, now child of lo
        ra = old; rb = lo;       // continue merging old parent with lo
    }
}

// binary search exact key in ascending array of KC ints (padded IMAX)
__device__ __forceinline__ int bsearch_k(const int* a, int key) {
    int lo = 0, hi = KC;
    while (lo < hi) { int m = (lo + hi) >> 1; if (a[m] < key) lo = m + 1; else hi = m; }
    return (lo < KC && a[lo] == key) ? lo : -1;
}

// ---------------- kernels ----------------
__global__ void k_init(const float* __restrict__ in, const float* __restrict__ tg,
                       int* __restrict__ labP, int* __restrict__ labG) {
    int g = blockIdx.x * blockDim.x + threadIdx.x;
    if (g >= PN) return;
    int i = g & (HWN - 1);
    labP[g] = (in[g] > 0.0f) ? i : SENT;   // sigmoid(x)>0.5 <=> x>0
    labG[g] = (tg[g] > 0.5f) ? i : SENT;
}

__device__ __forceinline__ void mergePixel(int* L, int i) {
    if (L[i] >= SENT) return;
    int r = i >> 9, c = i & 511;
    if (c > 0 && L[i - 1] < SENT) unite(L, i, i - 1);
    if (r > 0) {
        if (L[i - WW] < SENT) unite(L, i, i - WW);
        if (c > 0 && L[i - WW - 1] < SENT) unite(L, i, i - WW - 1);
        if (c < WW - 1 && L[i - WW + 1] < SENT) unite(L, i, i - WW + 1);
    }
}

__global__ void k_merge(int* __restrict__ labP, int* __restrict__ labG) {
    int g = blockIdx.x * blockDim.x + threadIdx.x;
    if (g >= PN) return;
    int b = g >> 18, i = g & (HWN - 1);
    mergePixel(labP + (b << 18), i);
    mergePixel(labG + (b << 18), i);
}

__global__ void k_flatten(int* __restrict__ labP, int* __restrict__ labG,
                          int* __restrict__ rootsP, int* __restrict__ rootsG,
                          int* __restrict__ cntP, int* __restrict__ cntG) {
    int g = blockIdx.x * blockDim.x + threadIdx.x;
    if (g >= PN) return;
    int b = g >> 18, i = g & (HWN - 1);
    int* LP = labP + (b << 18);
    if (LP[i] < SENT) {
        int ro = findRoot(LP, i);
        LP[i] = ro;
        if (ro == i) { int pos = atomicAdd(&cntP[b], 1); if (pos < RCAP) rootsP[b * RCAP + pos] = i; }
    }
    int* LG = labG + (b << 18);
    if (LG[i] < SENT) {
        int ro = findRoot(LG, i);
        LG[i] = ro;
        if (ro == i) { int pos = atomicAdd(&cntG[b], 1); if (pos < RCAP) rootsG[b * RCAP + pos] = i; }
    }
}

// one block per (image, mask): bitonic sort roots ascending, keep first KC
__global__ void k_sort(const int* __restrict__ rootsP, const int* __restrict__ rootsG,
                       const int* __restrict__ cntP, const int* __restrict__ cntG,
                       int* __restrict__ compP, int* __restrict__ compG,
                       int* __restrict__ ccntP, int* __restrict__ ccntG) {
    __shared__ int s[RCAP];
    int b = blockIdx.x >> 1;
    int which = blockIdx.x & 1;
    const int* roots = which ? rootsG : rootsP;
    const int* cnt   = which ? cntG : cntP;
    int n = min(cnt[b], RCAP);
    for (int t = threadIdx.x; t < RCAP; t += blockDim.x)
        s[t] = (t < n) ? roots[b * RCAP + t] : IMAX;
    __syncthreads();
    for (int k = 2; k <= RCAP; k <<= 1) {
        for (int j = k >> 1; j > 0; j >>= 1) {
            for (int t = threadIdx.x; t < RCAP; t += blockDim.x) {
                int ixj = t ^ j;
                if (ixj > t) {
                    int a = s[t], bb = s[ixj];
                    bool up = ((t & k) == 0);
                    if ((a > bb) == up) { s[t] = bb; s[ixj] = a; }
                }
            }
            __syncthreads();
        }
    }
    int cc = min(cnt[b], KC);
    int* comp = which ? compG : compP;
    int* ccnt = which ? ccntG : ccntP;
    for (int t = threadIdx.x; t < KC; t += blockDim.x)
        comp[b * KC + t] = (t < cc) ? s[t] : IMAX;
    if (threadIdx.x == 0) ccnt[b] = cc;
}

// region stats (exact int sums) + overlap flags, LDS-aggregated per block
__global__ void k_stats(const float* __restrict__ in, const float* __restrict__ tg,
                        const int* __restrict__ labP, const int* __restrict__ labG,
                        const int* __restrict__ compP, const int* __restrict__ compG,
                        int* __restrict__ pA, int* __restrict__ pR, int* __restrict__ pC,
                        int* __restrict__ gA, int* __restrict__ gR, int* __restrict__ gC,
                        int* __restrict__ ovP, int* __restrict__ ovG) {
    __shared__ int sLP[KC], sLG[KC];
    __shared__ int aP[KC], rP[KC], cP[KC], aG[KC], rG[KC], cG[KC];
    __shared__ int oP[KC], oG[KC];
    int b = blockIdx.x >> 10;                       // 1024 blocks per image
    int i = ((blockIdx.x & 1023) << 8) + threadIdx.x;
    for (int t = threadIdx.x; t < KC; t += TPB) {
        sLP[t] = compP[b * KC + t]; sLG[t] = compG[b * KC + t];
        aP[t] = rP[t] = cP[t] = 0; aG[t] = rG[t] = cG[t] = 0;
        oP[t] = oG[t] = 0;
    }
    __syncthreads();
    int g = (b << 18) + i;
    bool pred = in[g] > 0.0f;
    bool gtm  = tg[g] > 0.5f;
    int r = i >> 9, c = i & 511;
    if (pred) {
        int cid = bsearch_k(sLP, labP[g]);
        if (cid >= 0) {
            atomicAdd(&aP[cid], 1); atomicAdd(&rP[cid], r); atomicAdd(&cP[cid], c);
            if (gtm) oP[cid] = 1;
        }
    }
    if (gtm) {
        int cid = bsearch_k(sLG, labG[g]);
        if (cid >= 0) {
            atomicAdd(&aG[cid], 1); atomicAdd(&rG[cid], r); atomicAdd(&cG[cid], c);
            if (pred) oG[cid] = 1;
        }
    }
    __syncthreads();
    for (int t = threadIdx.x; t < KC; t += TPB) {
        if (aP[t]) { atomicAdd(&pA[b*KC+t], aP[t]); atomicAdd(&pR[b*KC+t], rP[t]); atomicAdd(&pC[b*KC+t], cP[t]); }
        if (oP[t]) atomicOr(&ovP[b*KC+t], 1);
        if (aG[t]) { atomicAdd(&gA[b*KC+t], aG[t]); atomicAdd(&gR[b*KC+t], rG[t]); atomicAdd(&gC[b*KC+t], cG[t]); }
        if (oG[t]) atomicOr(&ovG[b*KC+t], 1);
    }
}

// per-image: nearest gt centroid per pred region, region errors
__global__ void k_match(const int* __restrict__ pA, const int* __restrict__ pR, const int* __restrict__ pC,
                        const int* __restrict__ gA, const int* __restrict__ gR, const int* __restrict__ gC,
                        const int* __restrict__ ovP, const int* __restrict__ ccntP, const int* __restrict__ ccntG,
                        float* __restrict__ eP, float* __restrict__ eG) {
    __shared__ float sA[KC], sR[KC], sC[KC];
    int b = blockIdx.x;
    int t = threadIdx.x;                           // block = 512 = KC
    int ccg = ccntG[b], ccp = ccntP[b];
    {
        int a = gA[b * KC + t];
        float fa = (float)a;
        float d = fmaxf(fa, 1.0f);
        sA[t] = fa;
        sR[t] = (float)gR[b * KC + t] / d;
        sC[t] = (float)gC[b * KC + t] / d;
    }
    __syncthreads();
    float e_eff = 0.0f;
    int nn = 0;
    if (t < ccp) {
        float pa = (float)pA[b * KC + t];
        float dd = fmaxf(pa, 1.0f);
        float pcr = (float)pR[b * KC + t] / dd;
        float pcc = (float)pC[b * KC + t] / dd;
        float best = INFINITY;
        for (int gi = 0; gi < ccg; gi++) {
            float dr = pcr - sR[gi], dc = pcc - sC[gi];
            float d2 = dr * dr + dc * dc;
            if (d2 < best) { best = d2; nn = gi; }  // first-min ties like argmin
        }
        if (ccg > 0 && ovP[b * KC + t]) {
            float ratio = 1.0f - sA[nn] / dd;
            e_eff = fminf(fabsf(1.0f - expf(ratio)), 1.0f);
        }
    }
    eP[b * KC + t] = e_eff;
    if (e_eff > 0.0f) atomicMax((int*)&eG[b * KC + nn], __float_as_int(e_eff));
}

// per-pixel error rules + fused loss/metric reduction
__global__ void k_final(const float* __restrict__ in, const float* __restrict__ tg,
                        const int* __restrict__ labP, const int* __restrict__ labG,
                        const int* __restrict__ compP, const int* __restrict__ compG,
                        const int* __restrict__ ovP, const int* __restrict__ ovG,
                        const float* __restrict__ eP, const float* __restrict__ eG,
                        const int* __restrict__ ccntG, double* __restrict__ acc) {
    __shared__ int sLP[KC], sLG[KC], sOP[KC], sOG[KC];
    __shared__ float sEP[KC], sEG[KC];
    __shared__ double red[TPB];
    int b = blockIdx.x >> 10;
    int i = ((blockIdx.x & 1023) << 8) + threadIdx.x;
    for (int t = threadIdx.x; t < KC; t += TPB) {
        sLP[t] = compP[b*KC+t]; sLG[t] = compG[b*KC+t];
        sOP[t] = ovP[b*KC+t];   sOG[t] = ovG[b*KC+t];
        sEP[t] = eP[b*KC+t];    sEG[t] = eG[b*KC+t];
    }
    __syncthreads();
    int g = (b << 18) + i;
    float x = in[g], tt = tg[g];
    bool pred = x > 0.0f, gtm = tt > 0.5f;
    bool hasGt = ccntG[b] > 0;
    float pe = 0.0f;
    if (pred) {
        if (!hasGt) pe = 1.0f;
        else {
            int cid = bsearch_k(sLP, labP[g]);
            int ov = (cid >= 0) ? sOP[cid] : 1;
            if (!ov) pe = 1.0f;
            else if (!gtm) pe = (cid >= 0) ? sEP[cid] : 0.0f;   // pred px, gt!=1: region error
        }
    }
    if (gtm) {
        int gc = bsearch_k(sLG, labG[g]);
        if (!pred) pe = fmaxf(pe, (gc >= 0) ? sEG[gc] : 0.0f);  // gt px, pred<1
        int ovg = (gc >= 0) ? sOG[gc] : 1;
        if (!ovg) pe = 1.0f;                                     // final override
    }
    float score = 1.0f / (1.0f + expf(-x));
    float lm = (1.0f / (1.0f + expf(-(score + 1.0f) * pe)) - 0.5f) * 2.0f;

    // reductions: sum(lm), sum(pe), count(pe!=0)
    red[threadIdx.x] = (double)lm; __syncthreads();
    for (int s = TPB >> 1; s > 0; s >>= 1) { if (threadIdx.x < s) red[threadIdx.x] += red[threadIdx.x + s]; __syncthreads(); }
    if (threadIdx.x == 0) atomicAdd(&acc[0], red[0]);
    __syncthreads();
    red[threadIdx.x] = (double)pe; __syncthreads();
    for (int s = TPB >> 1; s > 0; s >>= 1) { if (threadIdx.x < s) red[threadIdx.x] += red[threadIdx.x + s]; __syncthreads(); }
    if (threadIdx.x == 0) atomicAdd(&acc[1], red[0]);
    __syncthreads();
    red[threadIdx.x] = (pe != 0.0f) ? 1.0 : 0.0; __syncthreads();
    for (int s = TPB >> 1; s > 0; s >>= 1) { if (threadIdx.x < s) red[threadIdx.x] += red[threadIdx.x + s]; __syncthreads(); }
    if (threadIdx.x == 0) atomicAdd(&acc[2], red[0]);
}

__global__ void k_out(const double* __restrict__ acc, float* __restrict__ out) {
    out[0] = (float)(acc[0] / (double)PN);
    out[1] = (float)(1.0 - acc[1] / (double)PN);
    out[2] = (float)(1.0 - acc[1] / acc[2]);
}

extern "C" void kernel_launch(void* const* d_in, const int* in_sizes, int n_in,
                              void* d_out, int out_size, void* d_ws, size_t ws_size,
                              hipStream_t stream) {
    const float* in = (const float*)d_in[0];
    const float* tg = (const float*)d_in[1];
    // d_in[2] = epoch, unused by forward

    char* w = (char*)d_ws;
    size_t off = 0;
    int* labP = (int*)(w + off); off += (size_t)PN * 4;
    int* labG = (int*)(w + off); off += (size_t)PN * 4;
    int* rootsP = (int*)(w + off); off += (size_t)NB * RCAP * 4;
    int* rootsG = (int*)(w + off); off += (size_t)NB * RCAP * 4;
    size_t zoff = off;
    int* cntP  = (int*)(w + off); off += NB * 4;
    int* cntG  = (int*)(w + off); off += NB * 4;
    int* ccntP = (int*)(w + off); off += NB * 4;
    int* ccntG = (int*)(w + off); off += NB * 4;
    int* compP = (int*)(w + off); off += (size_t)NB * KC * 4;
    int* compG = (int*)(w + off); off += (size_t)NB * KC * 4;
    int* pA = (int*)(w + off); off += (size_t)NB * KC * 4;
    int* pR = (int*)(w + off); off += (size_t)NB * KC * 4;
    int* pC = (int*)(w + off); off += (size_t)NB * KC * 4;
    int* gA = (int*)(w + off); off += (size_t)NB * KC * 4;
    int* gR = (int*)(w + off); off += (size_t)NB * KC * 4;
    int* gC = (int*)(w + off); off += (size_t)NB * KC * 4;
    int* ovP = (int*)(w + off); off += (size_t)NB * KC * 4;
    int* ovG = (int*)(w + off); off += (size_t)NB * KC * 4;
    float* eP = (float*)(w + off); off += (size_t)NB * KC * 4;
    float* eG = (float*)(w + off); off += (size_t)NB * KC * 4;
    double* acc = (double*)(w + off); off += 4 * 8;

    // zero all control/stat/accumulator state (fresh every call)
    hipMemsetAsync(w + zoff, 0, off - zoff, stream);

    int nblk = PN / TPB;  // 16384
    k_init<<<nblk, TPB, 0, stream>>>(in, tg, labP, labG);
    k_merge<<<nblk, TPB, 0, stream>>>(labP, labG);
    k_flatten<<<nblk, TPB, 0, stream>>>(labP, labG, rootsP, rootsG, cntP, cntG);
    k_sort<<<2 * NB, TPB, 0, stream>>>(rootsP, rootsG, cntP, cntG, compP, compG, ccntP, ccntG);
    k_stats<<<nblk, TPB, 0, stream>>>(in, tg, labP, labG, compP, compG,
                                      pA, pR, pC, gA, gR, gC, ovP, ovG);
    k_match<<<NB, KC, 0, stream>>>(pA, pR, pC, gA, gR, gC, ovP, ccntP, ccntG, eP, eG);
    k_final<<<nblk, TPB, 0, stream>>>(in, tg, labP, labG, compP, compG,
                                      ovP, ovG, eP, eG, ccntG, acc);
    k_out<<<1, 1, 0, stream>>>(acc, (float*)d_out);
}

// Round 2
// 1666.778 us; speedup vs baseline: 1.5420x; 1.5420x over previous
//
#include <hip/hip_runtime.h>

#define NB 16
#define HH 512
#define WW 512
#define HWN (HH * WW)            // 262144 = 1<<18
#define SENT HWN                  // background sentinel
#define KC 512                    // max regions kept per image
#define RCAP 4096                 // root-collection capacity per image
#define PN (NB * HWN)
#define TPB 256
#define IMAX 0x7FFFFFFF
#define TS 64                     // CCL tile side
#define TSQ (TS * TS)             // 4096, local sentinel

// ---------------- union-find helpers (global mem) ----------------
__device__ __forceinline__ int findRoot(int* L, int i) {
    int p = L[i];
    while (p != i) { i = p; p = L[i]; }
    return i;
}

__device__ __forceinline__ void unite(int* L, int a, int b) {
    int ra = findRoot(L, a);
    int rb = findRoot(L, b);
    while (ra != rb) {
        int lo = min(ra, rb), hi = max(ra, rb);
        int old = atomicMin(&L[hi], lo);
        if (old == hi) return;
        ra = old; rb = lo;
    }
}

// ---------------- union-find helpers (LDS) ----------------
__device__ __forceinline__ int findRootL(int* s, int i) {
    int p = s[i];
    while (p != i) { i = p; p = s[i]; }
    return i;
}

__device__ __forceinline__ void uniteL(int* s, int a, int b) {
    int ra = findRootL(s, a);
    int rb = findRootL(s, b);
    while (ra != rb) {
        int lo = min(ra, rb), hi = max(ra, rb);
        int old = atomicMin(&s[hi], lo);
        if (old == hi) return;
        ra = old; rb = lo;
    }
}

__device__ __forceinline__ void mergeL(int* s, int t, int lr, int lc) {
    if (s[t] >= TSQ) return;
    if (lc > 0 && s[t - 1] < TSQ) uniteL(s, t, t - 1);
    if (lr > 0) {
        if (s[t - TS] < TSQ) uniteL(s, t, t - TS);
        if (lc > 0 && s[t - TS - 1] < TSQ) uniteL(s, t, t - TS - 1);
        if (lc < TS - 1 && s[t - TS + 1] < TSQ) uniteL(s, t, t - TS + 1);
    }
}

// binary search exact key in ascending array of KC ints (padded IMAX)
__device__ __forceinline__ int bsearch_k(const int* a, int key) {
    int lo = 0, hi = KC;
    while (lo < hi) { int m = (lo + hi) >> 1; if (a[m] < key) lo = m + 1; else hi = m; }
    return (lo < KC && a[lo] == key) ? lo : -1;
}

// ---------------- kernels ----------------
// Per-tile CCL fully in LDS; writes labels pre-collapsed to tile-root global index.
__global__ void k_local(const float* __restrict__ in, const float* __restrict__ tg,
                        int* __restrict__ labP, int* __restrict__ labG) {
    __shared__ int sp[TSQ];
    __shared__ int sg[TSQ];
    int b = blockIdx.x >> 6;            // 64 tiles per image (8x8)
    int tile = blockIdx.x & 63;
    int r0 = (tile >> 3) * TS, c0 = (tile & 7) * TS;
    int base = (b << 18);
    for (int t = threadIdx.x; t < TSQ; t += TPB) {
        int lr = t >> 6, lc = t & 63;
        int g = base + ((r0 + lr) << 9) + (c0 + lc);
        sp[t] = (in[g] > 0.0f) ? t : TSQ;   // sigmoid(x)>0.5 <=> x>0
        sg[t] = (tg[g] > 0.5f) ? t : TSQ;
    }
    __syncthreads();
    for (int t = threadIdx.x; t < TSQ; t += TPB) {
        int lr = t >> 6, lc = t & 63;
        mergeL(sp, t, lr, lc);
        mergeL(sg, t, lr, lc);
    }
    __syncthreads();
    for (int t = threadIdx.x; t < TSQ; t += TPB) {
        int lr = t >> 6, lc = t & 63;
        int g = base + ((r0 + lr) << 9) + (c0 + lc);
        int rp = sp[t], rg = sg[t];
        if (rp < TSQ) {
            int ro = findRootL(sp, t);
            labP[g] = ((r0 + (ro >> 6)) << 9) + (c0 + (ro & 63));
        } else labP[g] = SENT;
        if (rg < TSQ) {
            int ro = findRootL(sg, t);
            labG[g] = ((r0 + (ro >> 6)) << 9) + (c0 + (ro & 63));
        } else labG[g] = SENT;
    }
}

__device__ __forceinline__ void processB(int* L, int i, int r, int c, int kind) {
    if (L[i] >= SENT) return;
    if (kind == 1) {            // c%64==0, c>0: w and nw edges cross the tile edge
        if (L[i - 1] < SENT) unite(L, i, i - 1);
        if (r > 0 && L[i - WW - 1] < SENT) unite(L, i, i - WW - 1);
    } else if (kind == 2) {     // c%64==63, c<511: ne edge crosses
        if (r > 0 && c < WW - 1 && L[i - WW + 1] < SENT) unite(L, i, i - WW + 1);
    } else {                    // r%64==0, r>0: n, nw, ne cross
        if (L[i - WW] < SENT) unite(L, i, i - WW);
        if (c > 0 && L[i - WW - 1] < SENT) unite(L, i, i - WW - 1);
        if (c < WW - 1 && L[i - WW + 1] < SENT) unite(L, i, i - WW + 1);
    }
}

// Cross-tile merges only: 21 boundary lines x 512 per image per mask.
__global__ void k_bmerge(int* __restrict__ labP, int* __restrict__ labG) {
    const int PER = 21 * 512;
    int idx = blockIdx.x * blockDim.x + threadIdx.x;
    if (idx >= NB * PER) return;
    int b = idx / PER, rem = idx % PER;
    int kind = rem / (7 * 512);
    int q = (rem % (7 * 512)) >> 9;
    int u = rem & 511;
    int r, c;
    if (kind == 0)      { r = TS * (q + 1); c = u; }
    else if (kind == 1) { c = TS * (q + 1); r = u; }
    else                { c = TS * q + 63;  r = u; }
    int i = (r << 9) | c;
    processB(labP + (b << 18), i, r, c, kind);
    processB(labG + (b << 18), i, r, c, kind);
}

__global__ void k_flatten(int* __restrict__ labP, int* __restrict__ labG,
                          int* __restrict__ rootsP, int* __restrict__ rootsG,
                          int* __restrict__ cntP, int* __restrict__ cntG) {
    int g = blockIdx.x * blockDim.x + threadIdx.x;
    if (g >= PN) return;
    int b = g >> 18, i = g & (HWN - 1);
    int* LP = labP + (b << 18);
    if (LP[i] < SENT) {
        int ro = findRoot(LP, i);
        LP[i] = ro;
        if (ro == i) { int pos = atomicAdd(&cntP[b], 1); if (pos < RCAP) rootsP[b * RCAP + pos] = i; }
    }
    int* LG = labG + (b << 18);
    if (LG[i] < SENT) {
        int ro = findRoot(LG, i);
        LG[i] = ro;
        if (ro == i) { int pos = atomicAdd(&cntG[b], 1); if (pos < RCAP) rootsG[b * RCAP + pos] = i; }
    }
}

// one block per (image, mask): bitonic sort roots ascending, keep first KC
__global__ void k_sort(const int* __restrict__ rootsP, const int* __restrict__ rootsG,
                       const int* __restrict__ cntP, const int* __restrict__ cntG,
                       int* __restrict__ compP, int* __restrict__ compG,
                       int* __restrict__ ccntP, int* __restrict__ ccntG) {
    __shared__ int s[RCAP];
    int b = blockIdx.x >> 1;
    int which = blockIdx.x & 1;
    const int* roots = which ? rootsG : rootsP;
    const int* cnt   = which ? cntG : cntP;
    int n = min(cnt[b], RCAP);
    for (int t = threadIdx.x; t < RCAP; t += blockDim.x)
        s[t] = (t < n) ? roots[b * RCAP + t] : IMAX;
    __syncthreads();
    for (int k = 2; k <= RCAP; k <<= 1) {
        for (int j = k >> 1; j > 0; j >>= 1) {
            for (int t = threadIdx.x; t < RCAP; t += blockDim.x) {
                int ixj = t ^ j;
                if (ixj > t) {
                    int a = s[t], bb = s[ixj];
                    bool up = ((t & k) == 0);
                    if ((a > bb) == up) { s[t] = bb; s[ixj] = a; }
                }
            }
            __syncthreads();
        }
    }
    int cc = min(cnt[b], KC);
    int* comp = which ? compG : compP;
    int* ccnt = which ? ccntG : ccntP;
    for (int t = threadIdx.x; t < KC; t += blockDim.x)
        comp[b * KC + t] = (t < cc) ? s[t] : IMAX;
    if (threadIdx.x == 0) ccnt[b] = cc;
}

// region stats (exact int sums) + overlap flags, LDS-aggregated per block
__global__ void k_stats(const float* __restrict__ in, const float* __restrict__ tg,
                        const int* __restrict__ labP, const int* __restrict__ labG,
                        const int* __restrict__ compP, const int* __restrict__ compG,
                        int* __restrict__ pA, int* __restrict__ pR, int* __restrict__ pC,
                        int* __restrict__ gA, int* __restrict__ gR, int* __restrict__ gC,
                        int* __restrict__ ovP, int* __restrict__ ovG) {
    __shared__ int sLP[KC], sLG[KC];
    __shared__ int aP[KC], rP[KC], cP[KC], aG[KC], rG[KC], cG[KC];
    __shared__ int oP[KC], oG[KC];
    int b = blockIdx.x >> 10;                       // 1024 blocks per image
    int i = ((blockIdx.x & 1023) << 8) + threadIdx.x;
    for (int t = threadIdx.x; t < KC; t += TPB) {
        sLP[t] = compP[b * KC + t]; sLG[t] = compG[b * KC + t];
        aP[t] = rP[t] = cP[t] = 0; aG[t] = rG[t] = cG[t] = 0;
        oP[t] = oG[t] = 0;
    }
    __syncthreads();
    int g = (b << 18) + i;
    bool pred = in[g] > 0.0f;
    bool gtm  = tg[g] > 0.5f;
    int r = i >> 9, c = i & 511;
    if (pred) {
        int cid = bsearch_k(sLP, labP[g]);
        if (cid >= 0) {
            atomicAdd(&aP[cid], 1); atomicAdd(&rP[cid], r); atomicAdd(&cP[cid], c);
            if (gtm) oP[cid] = 1;
        }
    }
    if (gtm) {
        int cid = bsearch_k(sLG, labG[g]);
        if (cid >= 0) {
            atomicAdd(&aG[cid], 1); atomicAdd(&rG[cid], r); atomicAdd(&cG[cid], c);
            if (pred) oG[cid] = 1;
        }
    }
    __syncthreads();
    for (int t = threadIdx.x; t < KC; t += TPB) {
        if (aP[t]) { atomicAdd(&pA[b*KC+t], aP[t]); atomicAdd(&pR[b*KC+t], rP[t]); atomicAdd(&pC[b*KC+t], cP[t]); }
        if (oP[t]) atomicOr(&ovP[b*KC+t], 1);
        if (aG[t]) { atomicAdd(&gA[b*KC+t], aG[t]); atomicAdd(&gR[b*KC+t], rG[t]); atomicAdd(&gC[b*KC+t], cG[t]); }
        if (oG[t]) atomicOr(&ovG[b*KC+t], 1);
    }
}

// per-image: nearest gt centroid per pred region, region errors
__global__ void k_match(const int* __restrict__ pA, const int* __restrict__ pR, const int* __restrict__ pC,
                        const int* __restrict__ gA, const int* __restrict__ gR, const int* __restrict__ gC,
                        const int* __restrict__ ovP, const int* __restrict__ ccntP, const int* __restrict__ ccntG,
                        float* __restrict__ eP, float* __restrict__ eG) {
    __shared__ float sA[KC], sR[KC], sC[KC];
    int b = blockIdx.x;
    int t = threadIdx.x;                           // block = 512 = KC
    int ccg = ccntG[b], ccp = ccntP[b];
    {
        int a = gA[b * KC + t];
        float fa = (float)a;
        float d = fmaxf(fa, 1.0f);
        sA[t] = fa;
        sR[t] = (float)gR[b * KC + t] / d;
        sC[t] = (float)gC[b * KC + t] / d;
    }
    __syncthreads();
    float e_eff = 0.0f;
    int nn = 0;
    if (t < ccp) {
        float pa = (float)pA[b * KC + t];
        float dd = fmaxf(pa, 1.0f);
        float pcr = (float)pR[b * KC + t] / dd;
        float pcc = (float)pC[b * KC + t] / dd;
        float best = INFINITY;
        for (int gi = 0; gi < ccg; gi++) {
            float dr = pcr - sR[gi], dc = pcc - sC[gi];
            float d2 = dr * dr + dc * dc;
            if (d2 < best) { best = d2; nn = gi; }  // first-min ties like argmin
        }
        if (ccg > 0 && ovP[b * KC + t]) {
            float ratio = 1.0f - sA[nn] / dd;
            e_eff = fminf(fabsf(1.0f - expf(ratio)), 1.0f);
        }
    }
    eP[b * KC + t] = e_eff;
    if (e_eff > 0.0f) atomicMax((int*)&eG[b * KC + nn], __float_as_int(e_eff));
}

// per-pixel error rules + fused loss/metric reduction
__global__ void k_final(const float* __restrict__ in, const float* __restrict__ tg,
                        const int* __restrict__ labP, const int* __restrict__ labG,
                        const int* __restrict__ compP, const int* __restrict__ compG,
                        const int* __restrict__ ovP, const int* __restrict__ ovG,
                        const float* __restrict__ eP, const float* __restrict__ eG,
                        const int* __restrict__ ccntG, double* __restrict__ acc) {
    __shared__ int sLP[KC], sLG[KC], sOP[KC], sOG[KC];
    __shared__ float sEP[KC], sEG[KC];
    __shared__ double red[TPB];
    int b = blockIdx.x >> 10;
    int i = ((blockIdx.x & 1023) << 8) + threadIdx.x;
    for (int t = threadIdx.x; t < KC; t += TPB) {
        sLP[t] = compP[b*KC+t]; sLG[t] = compG[b*KC+t];
        sOP[t] = ovP[b*KC+t];   sOG[t] = ovG[b*KC+t];
        sEP[t] = eP[b*KC+t];    sEG[t] = eG[b*KC+t];
    }
    __syncthreads();
    int g = (b << 18) + i;
    float x = in[g], tt = tg[g];
    bool pred = x > 0.0f, gtm = tt > 0.5f;
    bool hasGt = ccntG[b] > 0;
    float pe = 0.0f;
    if (pred) {
        if (!hasGt) pe = 1.0f;
        else {
            int cid = bsearch_k(sLP, labP[g]);
            int ov = (cid >= 0) ? sOP[cid] : 1;
            if (!ov) pe = 1.0f;
            else if (!gtm) pe = (cid >= 0) ? sEP[cid] : 0.0f;   // pred px, gt!=1: region error
        }
    }
    if (gtm) {
        int gc = bsearch_k(sLG, labG[g]);
        if (!pred) pe = fmaxf(pe, (gc >= 0) ? sEG[gc] : 0.0f);  // gt px, pred<1
        int ovg = (gc >= 0) ? sOG[gc] : 1;
        if (!ovg) pe = 1.0f;                                     // final override
    }
    float score = 1.0f / (1.0f + expf(-x));
    float lm = (1.0f / (1.0f + expf(-(score + 1.0f) * pe)) - 0.5f) * 2.0f;

    red[threadIdx.x] = (double)lm; __syncthreads();
    for (int s = TPB >> 1; s > 0; s >>= 1) { if (threadIdx.x < s) red[threadIdx.x] += red[threadIdx.x + s]; __syncthreads(); }
    if (threadIdx.x == 0) atomicAdd(&acc[0], red[0]);
    __syncthreads();
    red[threadIdx.x] = (double)pe; __syncthreads();
    for (int s = TPB >> 1; s > 0; s >>= 1) { if (threadIdx.x < s) red[threadIdx.x] += red[threadIdx.x + s]; __syncthreads(); }
    if (threadIdx.x == 0) atomicAdd(&acc[1], red[0]);
    __syncthreads();
    red[threadIdx.x] = (pe != 0.0f) ? 1.0 : 0.0; __syncthreads();
    for (int s = TPB >> 1; s > 0; s >>= 1) { if (threadIdx.x < s) red[threadIdx.x] += red[threadIdx.x + s]; __syncthreads(); }
    if (threadIdx.x == 0) atomicAdd(&acc[2], red[0]);
}

__global__ void k_out(const double* __restrict__ acc, float* __restrict__ out) {
    out[0] = (float)(acc[0] / (double)PN);
    out[1] = (float)(1.0 - acc[1] / (double)PN);
    out[2] = (float)(1.0 - acc[1] / acc[2]);
}

extern "C" void kernel_launch(void* const* d_in, const int* in_sizes, int n_in,
                              void* d_out, int out_size, void* d_ws, size_t ws_size,
                              hipStream_t stream) {
    const float* in = (const float*)d_in[0];
    const float* tg = (const float*)d_in[1];
    // d_in[2] = epoch, unused by forward

    char* w = (char*)d_ws;
    size_t off = 0;
    int* labP = (int*)(w + off); off += (size_t)PN * 4;
    int* labG = (int*)(w + off); off += (size_t)PN * 4;
    int* rootsP = (int*)(w + off); off += (size_t)NB * RCAP * 4;
    int* rootsG = (int*)(w + off); off += (size_t)NB * RCAP * 4;
    size_t zoff = off;
    int* cntP  = (int*)(w + off); off += NB * 4;
    int* cntG  = (int*)(w + off); off += NB * 4;
    int* ccntP = (int*)(w + off); off += NB * 4;
    int* ccntG = (int*)(w + off); off += NB * 4;
    int* compP = (int*)(w + off); off += (size_t)NB * KC * 4;
    int* compG = (int*)(w + off); off += (size_t)NB * KC * 4;
    int* pA = (int*)(w + off); off += (size_t)NB * KC * 4;
    int* pR = (int*)(w + off); off += (size_t)NB * KC * 4;
    int* pC = (int*)(w + off); off += (size_t)NB * KC * 4;
    int* gA = (int*)(w + off); off += (size_t)NB * KC * 4;
    int* gR = (int*)(w + off); off += (size_t)NB * KC * 4;
    int* gC = (int*)(w + off); off += (size_t)NB * KC * 4;
    int* ovP = (int*)(w + off); off += (size_t)NB * KC * 4;
    int* ovG = (int*)(w + off); off += (size_t)NB * KC * 4;
    float* eP = (float*)(w + off); off += (size_t)NB * KC * 4;
    float* eG = (float*)(w + off); off += (size_t)NB * KC * 4;
    double* acc = (double*)(w + off); off += 4 * 8;

    // zero all control/stat/accumulator state (fresh every call)
    hipMemsetAsync(w + zoff, 0, off - zoff, stream);

    int nblk = PN / TPB;  // 16384
    k_local<<<NB * 64, TPB, 0, stream>>>(in, tg, labP, labG);
    {
        const int total = NB * 21 * 512;
        k_bmerge<<<(total + TPB - 1) / TPB, TPB, 0, stream>>>(labP, labG);
    }
    k_flatten<<<nblk, TPB, 0, stream>>>(labP, labG, rootsP, rootsG, cntP, cntG);
    k_sort<<<2 * NB, TPB, 0, stream>>>(rootsP, rootsG, cntP, cntG, compP, compG, ccntP, ccntG);
    k_stats<<<nblk, TPB, 0, stream>>>(in, tg, labP, labG, compP, compG,
                                      pA, pR, pC, gA, gR, gC, ovP, ovG);
    k_match<<<NB, KC, 0, stream>>>(pA, pR, pC, gA, gR, gC, ovP, ccntP, ccntG, eP, eG);
    k_final<<<nblk, TPB, 0, stream>>>(in, tg, labP, labG, compP, compG,
                                      ovP, ovG, eP, eG, ccntG, acc);
    k_out<<<1, 1, 0, stream>>>(acc, (float*)d_out);
}

// Round 3
// 260.855 us; speedup vs baseline: 9.8530x; 6.3897x over previous
//
#include <hip/hip_runtime.h>

#define NB 16
#define HH 512
#define WW 512
#define HWN (HH * WW)            // 262144 = 1<<18
#define SENT HWN                  // background sentinel
#define KC 512                    // max regions kept per image
#define RCAP 4096                 // root-collection capacity per image
#define PN (NB * HWN)
#define TPB 256
#define IMAX 0x7FFFFFFF
#define TS 64                     // CCL tile side
#define TSQ (TS * TS)             // 4096, local sentinel

// ---------------- union-find helpers (global mem) ----------------
__device__ __forceinline__ int findRoot(int* L, int i) {
    int p = L[i];
    while (p != i) { i = p; p = L[i]; }
    return i;
}

__device__ __forceinline__ void unite(int* L, int a, int b) {
    int ra = findRoot(L, a);
    int rb = findRoot(L, b);
    while (ra != rb) {
        int lo = min(ra, rb), hi = max(ra, rb);
        int old = atomicMin(&L[hi], lo);
        if (old == hi) return;
        ra = old; rb = lo;
    }
}

// ---------------- union-find helpers (LDS) ----------------
__device__ __forceinline__ int findRootL(int* s, int i) {
    int p = s[i];
    while (p != i) { i = p; p = s[i]; }
    return i;
}

__device__ __forceinline__ void uniteL(int* s, int a, int b) {
    int ra = findRootL(s, a);
    int rb = findRootL(s, b);
    while (ra != rb) {
        int lo = min(ra, rb), hi = max(ra, rb);
        int old = atomicMin(&s[hi], lo);
        if (old == hi) return;
        ra = old; rb = lo;
    }
}

// binary search exact key in ascending array of KC ints (padded IMAX)
__device__ __forceinline__ int bsearch_k(const int* a, int key) {
    int lo = 0, hi = KC;
    while (lo < hi) { int m = (lo + hi) >> 1; if (a[m] < key) lo = m + 1; else hi = m; }
    return (lo < KC && a[lo] == key) ? lo : -1;
}

// ---------------- kernels ----------------
// Per-tile CCL: run-based labels (ballot), reduced union rules, all in LDS.
__global__ __launch_bounds__(TPB) void k_local(const float* __restrict__ in, const float* __restrict__ tg,
                        int* __restrict__ labP, int* __restrict__ labG) {
    __shared__ int sp[TSQ];
    __shared__ int sg[TSQ];
    __shared__ unsigned long long rmP[TS], rmG[TS];
    int b = blockIdx.x >> 6;            // 64 tiles per image (8x8)
    int tile = blockIdx.x & 63;
    int r0 = (tile >> 3) << 6, c0 = (tile & 7) << 6;
    int base = (b << 18) + (r0 << 9) + c0;
    int wv = threadIdx.x >> 6, lane = threadIdx.x & 63;

    // phase 1: load, ballot row masks, run-start initial labels (no atomics)
    for (int lr = wv; lr < TS; lr += 4) {
        int g = base + (lr << 9) + lane;
        bool p = in[g] > 0.0f;          // sigmoid(x)>0.5 <=> x>0
        bool q = tg[g] > 0.5f;
        unsigned long long mp = __ballot(p);
        unsigned long long mq = __ballot(q);
        int t = (lr << 6) + lane;
        unsigned long long below = (lane == 0) ? 0ULL : ((~mp) & ((1ULL << lane) - 1ULL));
        int st = below ? (64 - __clzll(below)) : 0;
        sp[t] = p ? ((lr << 6) + st) : TSQ;
        below = (lane == 0) ? 0ULL : ((~mq) & ((1ULL << lane) - 1ULL));
        st = below ? (64 - __clzll(below)) : 0;
        sg[t] = q ? ((lr << 6) + st) : TSQ;
        if (lane == 0) { rmP[lr] = mp; rmG[lr] = mq; }
    }
    __syncthreads();

    // phase 2: inter-row unions, reduced rules (one union per adjacent run-pair)
    for (int lr = wv; lr < TS; lr += 4) {
        if (lr == 0) continue;
        int t = (lr << 6) + lane;
        {
            unsigned long long m = rmP[lr], a = rmP[lr - 1];
            if ((m >> lane) & 1ULL) {
                bool N  = (a >> lane) & 1ULL;
                bool W  = lane > 0  && ((m >> (lane - 1)) & 1ULL);
                bool NW = lane > 0  && ((a >> (lane - 1)) & 1ULL);
                bool E  = lane < 63 && ((m >> (lane + 1)) & 1ULL);
                bool NE = lane < 63 && ((a >> (lane + 1)) & 1ULL);
                if (N) { if (!(W && NW)) uniteL(sp, t, t - TS); }
                else {
                    if (NW && !W) uniteL(sp, t, t - TS - 1);
                    if (NE && !E) uniteL(sp, t, t - TS + 1);
                }
            }
        }
        {
            unsigned long long m = rmG[lr], a = rmG[lr - 1];
            if ((m >> lane) & 1ULL) {
                bool N  = (a >> lane) & 1ULL;
                bool W  = lane > 0  && ((m >> (lane - 1)) & 1ULL);
                bool NW = lane > 0  && ((a >> (lane - 1)) & 1ULL);
                bool E  = lane < 63 && ((m >> (lane + 1)) & 1ULL);
                bool NE = lane < 63 && ((a >> (lane + 1)) & 1ULL);
                if (N) { if (!(W && NW)) uniteL(sg, t, t - TS); }
                else {
                    if (NW && !W) uniteL(sg, t, t - TS - 1);
                    if (NE && !E) uniteL(sg, t, t - TS + 1);
                }
            }
        }
    }
    __syncthreads();

    // phase 3: resolve + write global labels (pre-collapsed to tile root)
    for (int lr = wv; lr < TS; lr += 4) {
        int t = (lr << 6) + lane;
        int g = base + (lr << 9) + lane;
        int v = sp[t];
        if (v < TSQ) {
            int ro = findRootL(sp, t);
            labP[g] = ((r0 + (ro >> 6)) << 9) + (c0 + (ro & 63));
        } else labP[g] = SENT;
        v = sg[t];
        if (v < TSQ) {
            int ro = findRootL(sg, t);
            labG[g] = ((r0 + (ro >> 6)) << 9) + (c0 + (ro & 63));
        } else labG[g] = SENT;
    }
}

__device__ __forceinline__ void processB(int* L, int i, int r, int c, int kind) {
    if (L[i] >= SENT) return;
    if (kind == 1) {            // c%64==0, c>0: w and nw cross the tile edge
        if (L[i - 1] < SENT) unite(L, i, i - 1);
        if (r > 0 && L[i - WW - 1] < SENT) unite(L, i, i - WW - 1);
    } else if (kind == 2) {     // c%64==63, c<511: ne crosses
        if (r > 0 && c < WW - 1 && L[i - WW + 1] < SENT) unite(L, i, i - WW + 1);
    } else {                    // r%64==0, r>0: n, nw, ne cross
        if (L[i - WW] < SENT) unite(L, i, i - WW);
        if (c > 0 && L[i - WW - 1] < SENT) unite(L, i, i - WW - 1);
        if (c < WW - 1 && L[i - WW + 1] < SENT) unite(L, i, i - WW + 1);
    }
}

// Cross-tile merges only: 21 boundary lines x 512 per image per mask.
__global__ void k_bmerge(int* __restrict__ labP, int* __restrict__ labG) {
    const int PER = 21 * 512;
    int idx = blockIdx.x * blockDim.x + threadIdx.x;
    if (idx >= NB * PER) return;
    int b = idx / PER, rem = idx % PER;
    int kind = rem / (7 * 512);
    int q = (rem % (7 * 512)) >> 9;
    int u = rem & 511;
    int r, c;
    if (kind == 0)      { r = TS * (q + 1); c = u; }
    else if (kind == 1) { c = TS * (q + 1); r = u; }
    else                { c = TS * q + 63;  r = u; }
    int i = (r << 9) | c;
    processB(labP + (b << 18), i, r, c, kind);
    processB(labG + (b << 18), i, r, c, kind);
}

__global__ void k_flatten(int* __restrict__ labP, int* __restrict__ labG,
                          int* __restrict__ rootsP, int* __restrict__ rootsG,
                          int* __restrict__ cntP, int* __restrict__ cntG) {
    int g = blockIdx.x * blockDim.x + threadIdx.x;
    if (g >= PN) return;
    int b = g >> 18, i = g & (HWN - 1);
    int* LP = labP + (b << 18);
    if (LP[i] < SENT) {
        int ro = findRoot(LP, i);
        LP[i] = ro;
        if (ro == i) { int pos = atomicAdd(&cntP[b], 1); if (pos < RCAP) rootsP[b * RCAP + pos] = i; }
    }
    int* LG = labG + (b << 18);
    if (LG[i] < SENT) {
        int ro = findRoot(LG, i);
        LG[i] = ro;
        if (ro == i) { int pos = atomicAdd(&cntG[b], 1); if (pos < RCAP) rootsG[b * RCAP + pos] = i; }
    }
}

// one block per (image, mask): size-adaptive bitonic sort of roots ascending
__global__ void k_sort(const int* __restrict__ rootsP, const int* __restrict__ rootsG,
                       const int* __restrict__ cntP, const int* __restrict__ cntG,
                       int* __restrict__ compP, int* __restrict__ compG,
                       int* __restrict__ ccntP, int* __restrict__ ccntG) {
    __shared__ int s[RCAP];
    int b = blockIdx.x >> 1;
    int which = blockIdx.x & 1;
    const int* roots = which ? rootsG : rootsP;
    const int* cnt   = which ? cntG : cntP;
    int n = min(cnt[b], RCAP);
    for (int t = threadIdx.x; t < RCAP; t += blockDim.x)
        s[t] = (t < n) ? roots[b * RCAP + t] : IMAX;
    __syncthreads();
    int m = 1; while (m < n) m <<= 1;   // sort only next_pow2(n) elements
    for (int k = 2; k <= m; k <<= 1) {
        for (int j = k >> 1; j > 0; j >>= 1) {
            for (int t = threadIdx.x; t < m; t += blockDim.x) {
                int ixj = t ^ j;
                if (ixj > t) {
                    int a = s[t], bb = s[ixj];
                    bool up = ((t & k) == 0);
                    if ((a > bb) == up) { s[t] = bb; s[ixj] = a; }
                }
            }
            __syncthreads();
        }
    }
    int cc = min(n, KC);
    int* comp = which ? compG : compP;
    int* ccnt = which ? ccntG : ccntP;
    for (int t = threadIdx.x; t < KC; t += blockDim.x)
        comp[b * KC + t] = (t < cc) ? s[t] : IMAX;
    if (threadIdx.x == 0) ccnt[b] = cc;
}

// region stats from labels only (pred <=> labP<SENT); wave-uniform fast path
__global__ __launch_bounds__(TPB) void k_stats(const int* __restrict__ labP, const int* __restrict__ labG,
                        const int* __restrict__ compP, const int* __restrict__ compG,
                        int* __restrict__ pA, int* __restrict__ pR, int* __restrict__ pC,
                        int* __restrict__ gA, int* __restrict__ gR, int* __restrict__ gC,
                        int* __restrict__ ovP, int* __restrict__ ovG) {
    __shared__ int sLP[KC], sLG[KC];
    __shared__ int aP[KC], rP[KC], cP[KC], aG[KC], rG[KC], cG[KC];
    __shared__ int oP[KC], oG[KC];
    int b = blockIdx.x >> 6;            // 64 blocks per image, 4096 px each
    int blk = blockIdx.x & 63;
    for (int t = threadIdx.x; t < KC; t += TPB) {
        sLP[t] = compP[b * KC + t]; sLG[t] = compG[b * KC + t];
        aP[t] = rP[t] = cP[t] = 0; aG[t] = rG[t] = cG[t] = 0;
        oP[t] = oG[t] = 0;
    }
    __syncthreads();
    int lane = threadIdx.x & 63;
    for (int k = 0; k < 16; k++) {
        int i = (blk << 12) + (k << 8) + threadIdx.x;
        int g = (b << 18) + i;
        int lp = labP[g], lg = labG[g];
        int r = i >> 9, c = i & 511;    // r uniform within a wave
        // pred side
        {
            bool set = lp < SENT;
            unsigned long long mb = __ballot(set);
            if (mb) {
                int src = __ffsll((long long)mb) - 1;
                int l0 = __shfl(lp, src);
                bool uni = __all(!set || lp == l0);
                bool ovl = __any(set && (lg < SENT));
                if (uni) {
                    int cid = bsearch_k(sLP, l0);
                    if (cid >= 0) {
                        int sc = set ? c : 0;
                        for (int o = 32; o; o >>= 1) sc += __shfl_xor(sc, o);
                        if (lane == src) {
                            int area = __popcll(mb);
                            atomicAdd(&aP[cid], area);
                            atomicAdd(&rP[cid], r * area);
                            atomicAdd(&cP[cid], sc);
                            if (ovl) oP[cid] = 1;
                        }
                    }
                } else if (set) {
                    int cid = bsearch_k(sLP, lp);
                    if (cid >= 0) {
                        atomicAdd(&aP[cid], 1); atomicAdd(&rP[cid], r); atomicAdd(&cP[cid], c);
                        if (lg < SENT) oP[cid] = 1;
                    }
                }
            }
        }
        // gt side
        {
            bool set = lg < SENT;
            unsigned long long mb = __ballot(set);
            if (mb) {
                int src = __ffsll((long long)mb) - 1;
                int l0 = __shfl(lg, src);
                bool uni = __all(!set || lg == l0);
                bool ovl = __any(set && (lp < SENT));
                if (uni) {
                    int cid = bsearch_k(sLG, l0);
                    if (cid >= 0) {
                        int sc = set ? c : 0;
                        for (int o = 32; o; o >>= 1) sc += __shfl_xor(sc, o);
                        if (lane == src) {
                            int area = __popcll(mb);
                            atomicAdd(&aG[cid], area);
                            atomicAdd(&rG[cid], r * area);
                            atomicAdd(&cG[cid], sc);
                            if (ovl) oG[cid] = 1;
                        }
                    }
                } else if (set) {
                    int cid = bsearch_k(sLG, lg);
                    if (cid >= 0) {
                        atomicAdd(&aG[cid], 1); atomicAdd(&rG[cid], r); atomicAdd(&cG[cid], c);
                        if (lp < SENT) oG[cid] = 1;
                    }
                }
            }
        }
    }
    __syncthreads();
    for (int t = threadIdx.x; t < KC; t += TPB) {
        if (aP[t]) { atomicAdd(&pA[b*KC+t], aP[t]); atomicAdd(&pR[b*KC+t], rP[t]); atomicAdd(&pC[b*KC+t], cP[t]); }
        if (oP[t]) atomicOr(&ovP[b*KC+t], 1);
        if (aG[t]) { atomicAdd(&gA[b*KC+t], aG[t]); atomicAdd(&gR[b*KC+t], rG[t]); atomicAdd(&gC[b*KC+t], cG[t]); }
        if (oG[t]) atomicOr(&ovG[b*KC+t], 1);
    }
}

// per-image: nearest gt centroid per pred region, region errors
__global__ void k_match(const int* __restrict__ pA, const int* __restrict__ pR, const int* __restrict__ pC,
                        const int* __restrict__ gA, const int* __restrict__ gR, const int* __restrict__ gC,
                        const int* __restrict__ ovP, const int* __restrict__ ccntP, const int* __restrict__ ccntG,
                        float* __restrict__ eP, float* __restrict__ eG) {
    __shared__ float sA[KC], sR[KC], sC[KC];
    int b = blockIdx.x;
    int t = threadIdx.x;                           // block = 512 = KC
    int ccg = ccntG[b], ccp = ccntP[b];
    {
        int a = gA[b * KC + t];
        float fa = (float)a;
        float d = fmaxf(fa, 1.0f);
        sA[t] = fa;
        sR[t] = (float)gR[b * KC + t] / d;
        sC[t] = (float)gC[b * KC + t] / d;
    }
    __syncthreads();
    float e_eff = 0.0f;
    int nn = 0;
    if (t < ccp) {
        float pa = (float)pA[b * KC + t];
        float dd = fmaxf(pa, 1.0f);
        float pcr = (float)pR[b * KC + t] / dd;
        float pcc = (float)pC[b * KC + t] / dd;
        float best = INFINITY;
        for (int gi = 0; gi < ccg; gi++) {
            float dr = pcr - sR[gi], dc = pcc - sC[gi];
            float d2 = dr * dr + dc * dc;
            if (d2 < best) { best = d2; nn = gi; }  // first-min ties like argmin
        }
        if (ccg > 0 && ovP[b * KC + t]) {
            float ratio = 1.0f - sA[nn] / dd;
            e_eff = fminf(fabsf(1.0f - expf(ratio)), 1.0f);
        }
    }
    eP[b * KC + t] = e_eff;
    if (e_eff > 0.0f) atomicMax((int*)&eG[b * KC + nn], __float_as_int(e_eff));
}

// per-pixel error rules + fused loss/metric reduction (labels-only masks)
__global__ __launch_bounds__(TPB) void k_final(const float* __restrict__ in,
                        const int* __restrict__ labP, const int* __restrict__ labG,
                        const int* __restrict__ compP, const int* __restrict__ compG,
                        const int* __restrict__ ovP, const int* __restrict__ ovG,
                        const float* __restrict__ eP, const float* __restrict__ eG,
                        const int* __restrict__ ccntG, double* __restrict__ acc) {
    __shared__ int sLP[KC], sLG[KC], sOP[KC], sOG[KC];
    __shared__ float sEP[KC], sEG[KC];
    __shared__ float pLm[4], pPe[4];
    __shared__ int pCnt[4];
    int b = blockIdx.x >> 6;
    int blk = blockIdx.x & 63;
    for (int t = threadIdx.x; t < KC; t += TPB) {
        sLP[t] = compP[b*KC+t]; sLG[t] = compG[b*KC+t];
        sOP[t] = ovP[b*KC+t];   sOG[t] = ovG[b*KC+t];
        sEP[t] = eP[b*KC+t];    sEG[t] = eG[b*KC+t];
    }
    __syncthreads();
    bool hasGt = ccntG[b] > 0;
    float aLm = 0.0f, aPe = 0.0f;
    int aCnt = 0;
    for (int k = 0; k < 16; k++) {
        int i = (blk << 12) + (k << 8) + threadIdx.x;
        int g = (b << 18) + i;
        int lp = labP[g], lg = labG[g];
        bool pred = lp < SENT, gtm = lg < SENT;
        if (!pred && !gtm) continue;     // pe=0 -> lm=0 exactly
        float pe = 0.0f;
        if (pred) {
            if (!hasGt) pe = 1.0f;
            else {
                int cid = bsearch_k(sLP, lp);
                int ov = (cid >= 0) ? sOP[cid] : 1;
                if (!ov) pe = 1.0f;
                else if (!gtm) pe = (cid >= 0) ? sEP[cid] : 0.0f;
            }
        }
        if (gtm) {
            int gc = bsearch_k(sLG, lg);
            if (!pred) pe = fmaxf(pe, (gc >= 0) ? sEG[gc] : 0.0f);
            int ovg = (gc >= 0) ? sOG[gc] : 1;
            if (!ovg) pe = 1.0f;
        }
        if (pe != 0.0f) {
            float x = in[g];
            float score = 1.0f / (1.0f + expf(-x));
            aLm += (1.0f / (1.0f + expf(-(score + 1.0f) * pe)) - 0.5f) * 2.0f;
            aPe += pe;
            aCnt++;
        }
    }
    for (int o = 32; o; o >>= 1) {
        aLm += __shfl_xor(aLm, o);
        aPe += __shfl_xor(aPe, o);
        aCnt += __shfl_xor(aCnt, o);
    }
    int wv = threadIdx.x >> 6, lane = threadIdx.x & 63;
    if (lane == 0) { pLm[wv] = aLm; pPe[wv] = aPe; pCnt[wv] = aCnt; }
    __syncthreads();
    if (threadIdx.x == 0) {
        double sl = 0, sp = 0; int sc = 0;
        for (int q = 0; q < 4; q++) { sl += pLm[q]; sp += pPe[q]; sc += pCnt[q]; }
        atomicAdd(&acc[0], sl);
        atomicAdd(&acc[1], sp);
        atomicAdd(&acc[2], (double)sc);
    }
}

__global__ void k_out(const double* __restrict__ acc, float* __restrict__ out) {
    out[0] = (float)(acc[0] / (double)PN);
    out[1] = (float)(1.0 - acc[1] / (double)PN);
    out[2] = (float)(1.0 - acc[1] / acc[2]);
}

extern "C" void kernel_launch(void* const* d_in, const int* in_sizes, int n_in,
                              void* d_out, int out_size, void* d_ws, size_t ws_size,
                              hipStream_t stream) {
    const float* in = (const float*)d_in[0];
    const float* tg = (const float*)d_in[1];
    // d_in[2] = epoch, unused by forward

    char* w = (char*)d_ws;
    size_t off = 0;
    int* labP = (int*)(w + off); off += (size_t)PN * 4;
    int* labG = (int*)(w + off); off += (size_t)PN * 4;
    int* rootsP = (int*)(w + off); off += (size_t)NB * RCAP * 4;
    int* rootsG = (int*)(w + off); off += (size_t)NB * RCAP * 4;
    size_t zoff = off;
    int* cntP  = (int*)(w + off); off += NB * 4;
    int* cntG  = (int*)(w + off); off += NB * 4;
    int* ccntP = (int*)(w + off); off += NB * 4;
    int* ccntG = (int*)(w + off); off += NB * 4;
    int* compP = (int*)(w + off); off += (size_t)NB * KC * 4;
    int* compG = (int*)(w + off); off += (size_t)NB * KC * 4;
    int* pA = (int*)(w + off); off += (size_t)NB * KC * 4;
    int* pR = (int*)(w + off); off += (size_t)NB * KC * 4;
    int* pC = (int*)(w + off); off += (size_t)NB * KC * 4;
    int* gA = (int*)(w + off); off += (size_t)NB * KC * 4;
    int* gR = (int*)(w + off); off += (size_t)NB * KC * 4;
    int* gC = (int*)(w + off); off += (size_t)NB * KC * 4;
    int* ovP = (int*)(w + off); off += (size_t)NB * KC * 4;
    int* ovG = (int*)(w + off); off += (size_t)NB * KC * 4;
    float* eP = (float*)(w + off); off += (size_t)NB * KC * 4;
    float* eG = (float*)(w + off); off += (size_t)NB * KC * 4;
    double* acc = (double*)(w + off); off += 4 * 8;

    // zero all control/stat/accumulator state (fresh every call)
    hipMemsetAsync(w + zoff, 0, off - zoff, stream);

    int nblk = PN / TPB;  // 16384
    k_local<<<NB * 64, TPB, 0, stream>>>(in, tg, labP, labG);
    {
        const int total = NB * 21 * 512;
        k_bmerge<<<(total + TPB - 1) / TPB, TPB, 0, stream>>>(labP, labG);
    }
    k_flatten<<<nblk, TPB, 0, stream>>>(labP, labG, rootsP, rootsG, cntP, cntG);
    k_sort<<<2 * NB, TPB, 0, stream>>>(rootsP, rootsG, cntP, cntG, compP, compG, ccntP, ccntG);
    k_stats<<<NB * 64, TPB, 0, stream>>>(labP, labG, compP, compG,
                                         pA, pR, pC, gA, gR, gC, ovP, ovG);
    k_match<<<NB, KC, 0, stream>>>(pA, pR, pC, gA, gR, gC, ovP, ccntP, ccntG, eP, eG);
    k_final<<<NB * 64, TPB, 0, stream>>>(in, labP, labG, compP, compG,
                                         ovP, ovG, eP, eG, ccntG, acc);
    k_out<<<1, 1, 0, stream>>>(acc, (float*)d_out);
}